// Round 13
// baseline (343.469 us; speedup 1.0000x reference)
//
#include <hip/hip_runtime.h>
#include <math.h>

// ---- problem constants ----
constexpr int kN   = 20000;
constexpr int kE   = 160000;
constexpr int kR   = 3;
constexpr int kL   = 2;
constexpr int kIN  = 64;
constexpr int kHID = 128;
constexpr int kH   = 16;
constexpr int kFH  = 8;
constexpr int kHD2 = 64;

typedef __bf16 bf16x8 __attribute__((ext_vector_type(8)));
typedef float  f32x4  __attribute__((ext_vector_type(4)));

__device__ __forceinline__ bf16x8 ldfrag(const __bf16* p) {
  return __builtin_bit_cast(bf16x8, *(const uint4*)p);
}
__device__ __forceinline__ f32x4 MF(bf16x8 a, bf16x8 b, f32x4 c) {
  return __builtin_amdgcn_mfma_f32_16x16x32_bf16(a, b, c, 0, 0, 0);
}

// split 8 f32 (optional BN+ReLU) into bf16 hi/lo fragments in-register
__device__ __forceinline__ void splitrow(const float* __restrict__ p, int koff,
                                         bool bn, const float* scS, const float* shS,
                                         bf16x8& hi, bf16x8& lo) {
  float4 xa = *(const float4*)(p + koff);
  float4 xb = *(const float4*)(p + koff + 4);
  float x[8] = {xa.x, xa.y, xa.z, xa.w, xb.x, xb.y, xb.z, xb.w};
  union { __bf16 b[8]; bf16x8 v; } uh, ul;
#pragma unroll
  for (int e = 0; e < 8; e++) {
    float y = x[e];
    if (bn) y = fmaxf(fmaf(y, scS[koff + e], shS[koff + e]), 0.f);
    __bf16 hb = (__bf16)y;
    uh.b[e] = hb;
    ul.b[e] = (__bf16)(y - (float)hb);
  }
  hi = uh.v; lo = ul.v;
}

// ============================================================================
// MFMA GEMM, bf16-split: C = [BN+ReLU?](A) @ W (+bias)(+res)
// bpasses=3: ah*bh + al*bh + ah*bl (~f32 precision) — for the h/MLP chain.
// bpasses=2: ah*bh + al*bh = h*W_hi (2^-9 rel err) — for z-gemm, whose output
//            is stored bf16 (2^-9 rounding) anyway; skips W_lo LDS staging.
// el/er epilogue (z-gemm): elb/erb[row*64 + rel*16 + head] from exact f32 acc.
// ============================================================================
__global__ __launch_bounds__(256) void mgemm_kernel(
    const float* __restrict__ A, const __bf16* __restrict__ WT,
    const float* __restrict__ bias, const float* __restrict__ resf, int resmode,
    const float* __restrict__ bnstat, const float* __restrict__ bng,
    const float* __restrict__ bnbt, float invn,
    float* __restrict__ statS,
    float* __restrict__ Cf, __bf16* __restrict__ Chi,
    const float* __restrict__ alb, const float* __restrict__ arb,
    float* __restrict__ elb, float* __restrict__ erb,
    int n, int k, int m, long wstride, long cstride, int bpasses) {
  __shared__ __bf16 Bh[64][136];   // +8 pad -> conflict-free frag reads
  __shared__ __bf16 Bl[64][136];
  __shared__ float scS[128], shS[128];
  const int t  = threadIdx.x;
  const int w  = t >> 6;
  const int l  = t & 63;
  const int lr = l & 15;
  const int lg = l >> 4;
  const int rb = blockIdx.x * 128 + w * 32;
  const int c0 = blockIdx.y * 64;
  const __bf16* Whi = WT + (size_t)blockIdx.z * wstride;
  const __bf16* Wlo = Whi + (size_t)k * m;
  if (Chi) Chi += (size_t)blockIdx.z * cstride;
  const float* al = alb ? alb + blockIdx.z * kHID : nullptr;
  const float* ar = arb ? arb + blockIdx.z * kHID : nullptr;
  if (elb) { elb += blockIdx.z * 16; erb += blockIdx.z * 16; }

  const bool bn = bnstat != nullptr;
  if (bn && t < k) {
    float mu  = bnstat[t] * invn;
    float var = bnstat[k + t] * invn - mu * mu;
    float s = bng[t] * rsqrtf(var + 1e-5f);
    scS[t] = s; shS[t] = bnbt[t] - mu * s;
  }
  const int kseg = k >> 3;
  for (int idx = t; idx < 64 * kseg; idx += 256) {
    int col = idx / kseg, seg = idx - col * kseg;
    *(uint4*)&Bh[col][seg * 8] = *(const uint4*)&Whi[(size_t)(c0 + col) * k + seg * 8];
    if (bpasses == 3)
      *(uint4*)&Bl[col][seg * 8] = *(const uint4*)&Wlo[(size_t)(c0 + col) * k + seg * 8];
  }
  __syncthreads();

  int r0 = rb + lr;      if (r0 > n - 1) r0 = n - 1;
  int r1 = rb + 16 + lr; if (r1 > n - 1) r1 = n - 1;
  f32x4 acc[2][4] = {};

  for (int ks = 0; ks < (k >> 5); ks++) {
    const int koff = ks * 32 + lg * 8;
    bf16x8 a0h, a0l, a1h, a1l;
    splitrow(&A[(size_t)r0 * k], koff, bn, scS, shS, a0h, a0l);
    splitrow(&A[(size_t)r1 * k], koff, bn, scS, shS, a1h, a1l);
#pragma unroll
    for (int j = 0; j < 4; j++) {
      bf16x8 bh = ldfrag(&Bh[j * 16 + lr][koff]);
      acc[0][j] = MF(a0h, bh, acc[0][j]);
      acc[0][j] = MF(a0l, bh, acc[0][j]);
      acc[1][j] = MF(a1h, bh, acc[1][j]);
      acc[1][j] = MF(a1l, bh, acc[1][j]);
      if (bpasses == 3) {
        bf16x8 bl = ldfrag(&Bl[j * 16 + lr][koff]);
        acc[0][j] = MF(a0h, bl, acc[0][j]);
        acc[1][j] = MF(a1h, bl, acc[1][j]);
      }
    }
  }

  // epilogue: D element (i,j,q) -> row rb+i*16+lg*4+q, col c0+j*16+lr
  float s[4] = {}, s2[4] = {};
#pragma unroll
  for (int i = 0; i < 2; i++) {
#pragma unroll
    for (int q = 0; q < 4; q++) {
      int row = rb + i * 16 + lg * 4 + q;
      bool ok = row < n;
#pragma unroll
      for (int j = 0; j < 4; j++) {
        int col = c0 + j * 16 + lr;
        float v = acc[i][j][q];
        if (bias) v += bias[col];
        size_t off = (size_t)row * m + col;
        if (ok) {
          if (resmode == 1) v += resf[off];
          else if (resmode == 2) v += fmaxf(fmaf(resf[off], scS[col], shS[col]), 0.f);
          if (Cf) Cf[off] = v;
          if (Chi) Chi[off] = (__bf16)v;
          s[j] += v; s2[j] += v * v;
        }
      }
    }
  }
  if (statS) {
    __syncthreads();
    float* red = (float*)&Bh[0][0];   // 512 floats scratch
#pragma unroll
    for (int j = 0; j < 4; j++) {
      float a = s[j], b = s2[j];
      a += __shfl_xor(a, 16, 64); a += __shfl_xor(a, 32, 64);
      b += __shfl_xor(b, 16, 64); b += __shfl_xor(b, 32, 64);
      if (lg == 0) { red[w * 64 + j * 16 + lr] = a; red[256 + w * 64 + j * 16 + lr] = b; }
    }
    __syncthreads();
    if (t < 64) {
      float a = red[t] + red[64 + t] + red[128 + t] + red[192 + t];
      float b = red[256 + t] + red[320 + t] + red[384 + t] + red[448 + t];
      atomicAdd(&statS[c0 + t], a);
      atomicAdd(&statS[m + c0 + t], b);
    }
  }
  if (al) {
#pragma unroll
    for (int i = 0; i < 2; i++) {
#pragma unroll
      for (int q = 0; q < 4; q++) {
        int row = rb + i * 16 + lg * 4 + q;
#pragma unroll
        for (int j = 0; j < 4; j++) {
          int col = c0 + j * 16 + lr;
          float zv = acc[i][j][q];
          float pl = zv * al[col];
          float pr = zv * ar[col];
          pl += __shfl_xor(pl, 1, 64); pl += __shfl_xor(pl, 2, 64); pl += __shfl_xor(pl, 4, 64);
          pr += __shfl_xor(pr, 1, 64); pr += __shfl_xor(pr, 2, 64); pr += __shfl_xor(pr, 4, 64);
          if ((lr & 7) == 0 && row < n) {
            int hd = col >> 3;   // global head 0..15
            elb[((size_t)row << 6) + hd] = pl;
            erb[((size_t)row << 6) + hd] = pr;
          }
        }
      }
    }
  }
}

// ---- weight transpose + bf16 hi/lo split prep ----
struct WDesc { const float* src; long doff; int k, m; };
struct WDescs { WDesc d[13]; };
__global__ void wprep_kernel(WDescs ds, __bf16* __restrict__ wt) {
  WDesc dd = ds.d[blockIdx.y];
  int idx = blockIdx.x * 256 + threadIdx.x;
  if (idx >= dd.k * dd.m) return;
  int row = idx / dd.m, col = idx - row * dd.m;
  float v = dd.src[idx];
  __bf16 hb = (__bf16)v;
  __bf16 lb = (__bf16)(v - (float)hb);
  wt[dd.doff + (size_t)col * dd.k + row] = hb;
  wt[dd.doff + (size_t)dd.k * dd.m + (size_t)col * dd.k + row] = lb;
}

// ---- CSR build ----
__global__ void hist_kernel(const int* __restrict__ dst, int* __restrict__ deg) {
  int r = blockIdx.y;
  int e = blockIdx.x * 256 + threadIdx.x;
  if (e < kE) atomicAdd(&deg[r * kN + dst[r * kE + e]], 1);
}

__global__ __launch_bounds__(1024) void csr_scan_kernel(const int* __restrict__ deg,
                                                        int* __restrict__ rowptr) {
  const int r = blockIdx.y;
  const int* dg = deg + r * kN;
  int* rp = rowptr + r * (kN + 1);
  const int t = threadIdx.x;
  constexpr int C = (kN + 1023) / 1024;   // 20
  const int base = t * C;
  int sum = 0;
#pragma unroll
  for (int i = 0; i < C; i++) {
    int j = base + i;
    if (j < kN) sum += dg[j];
  }
  __shared__ int warpTot[16];
  int lane = t & 63, wid = t >> 6;
  int v = sum;
  for (int off = 1; off < 64; off <<= 1) {
    int y = __shfl_up(v, off, 64);
    if (lane >= off) v += y;
  }
  if (lane == 63) warpTot[wid] = v;
  __syncthreads();
  int wadd = 0;
#pragma unroll
  for (int i = 0; i < 16; i++) if (i < wid) wadd += warpTot[i];
  int run = wadd + v - sum;
#pragma unroll
  for (int i = 0; i < C; i++) {
    int j = base + i;
    if (j < kN) { rp[j] = run; run += dg[j]; }
  }
  if (t == 1023) rp[kN] = run;
}

__global__ void scatter_kernel(const int* __restrict__ src, const int* __restrict__ dst,
                               const int* __restrict__ rowptr, int* __restrict__ cursor,
                               int* __restrict__ col) {
  int r = blockIdx.y;
  int e = blockIdx.x * 256 + threadIdx.x;
  if (e < kE) {
    int d = dst[r * kE + e];
    int p = atomicAdd(&cursor[r * kN + d], 1);
    col[r * kE + rowptr[r * (kN + 1) + d] + p] = src[r * kE + e];
  }
}

// ---- fused relation-softmax + edge softmax + aggregation ----
// thread per (dst, head); masked 8-wide batched edge loop: every edge load
// issues in an 8-deep batch (OOB lanes clamp to end-1 and get ex=0 -> exact).
__global__ void gat3_kernel(const int* __restrict__ rowptr, const int* __restrict__ colidx,
                            const ushort* __restrict__ z, const float* __restrict__ elb,
                            const float* __restrict__ erb,
                            const float* __restrict__ attn_pl, const float* __restrict__ gat_bl,
                            float* __restrict__ vv) {
  __shared__ float wsmS[kR * kHID], cvecS[kHID];
  int t = threadIdx.x;
  if (t < kHID) {
    float p0 = attn_pl[t], p1 = attn_pl[kHID + t], p2 = attn_pl[2 * kHID + t];
    float mx = fmaxf(p0, fmaxf(p1, p2));
    float e0 = __expf(p0 - mx), e1 = __expf(p1 - mx), e2 = __expf(p2 - mx);
    float si = 1.f / (e0 + e1 + e2);
    wsmS[t] = e0 * si; wsmS[kHID + t] = e1 * si; wsmS[2 * kHID + t] = e2 * si;
    cvecS[t] = (e0 * gat_bl[t] + e1 * gat_bl[kHID + t] + e2 * gat_bl[2 * kHID + t]) * si;
  }
  __syncthreads();
  int idx = blockIdx.x * 256 + t;
  if (idx >= kN * kH) return;
  int d = idx >> 4, hh = idx & 15;
  const int fo = hh << 3;
  float out[kFH];
#pragma unroll
  for (int f = 0; f < kFH; f++) out[f] = cvecS[fo + f];
  for (int r = 0; r < kR; r++) {
    const int* rp = rowptr + r * (kN + 1);
    const int* ci = colidx + (size_t)r * kE;
    const ushort* zr = z + (size_t)r * kN * kHID;
    const int ro = r * 16 + hh;
    float erd = erb[((size_t)d << 6) + ro];
    int beg = rp[d], end = rp[d + 1];
    float s = 0.f;
    float acc[kFH] = {};
    for (int p = beg; p < end; p += 8) {
      int q[8]; float ev[8]; uint4 zz[8];
#pragma unroll
      for (int u = 0; u < 8; u++) {
        int pp = p + u;
        q[u] = ci[pp < end ? pp : end - 1];
      }
#pragma unroll
      for (int u = 0; u < 8; u++) ev[u] = elb[((size_t)q[u] << 6) + ro];
#pragma unroll
      for (int u = 0; u < 8; u++) zz[u] = *(const uint4*)(zr + ((size_t)q[u] << 7) + fo);
#pragma unroll
      for (int u = 0; u < 8; u++) {
        float v = ev[u] + erd;
        v = v > 0.f ? v : 0.2f * v;
        float ex = (p + u < end) ? __expf(v) : 0.f;   // logits O(0.1): no overflow
        s += ex;
        acc[0] = fmaf(ex, __uint_as_float(zz[u].x << 16),         acc[0]);
        acc[1] = fmaf(ex, __uint_as_float(zz[u].x & 0xffff0000u), acc[1]);
        acc[2] = fmaf(ex, __uint_as_float(zz[u].y << 16),         acc[2]);
        acc[3] = fmaf(ex, __uint_as_float(zz[u].y & 0xffff0000u), acc[3]);
        acc[4] = fmaf(ex, __uint_as_float(zz[u].z << 16),         acc[4]);
        acc[5] = fmaf(ex, __uint_as_float(zz[u].z & 0xffff0000u), acc[5]);
        acc[6] = fmaf(ex, __uint_as_float(zz[u].w << 16),         acc[6]);
        acc[7] = fmaf(ex, __uint_as_float(zz[u].w & 0xffff0000u), acc[7]);
      }
    }
    float inv = s > 0.f ? 1.f / s : 0.f;
    const float* wp = wsmS + r * kHID + fo;
#pragma unroll
    for (int f = 0; f < kFH; f++) out[f] = fmaf(wp[f] * inv, acc[f], out[f]);
  }
  float4* vp = (float4*)(vv + ((size_t)d << 7) + fo);
  vp[0] = make_float4(out[0], out[1], out[2], out[3]);
  vp[1] = make_float4(out[4], out[5], out[6], out[7]);
}

// ---- final gemv: BN fold from raw stats + BN+ReLU + dot, all fused ----
__global__ void gemv_out_kernel(const float* __restrict__ A, const float* __restrict__ statS,
                                const float* __restrict__ g, const float* __restrict__ bt,
                                float invn, const float* __restrict__ w,
                                const float* __restrict__ b, float* __restrict__ out,
                                int n, int k) {
  __shared__ float scS[kHD2], shS[kHD2];
  int t = threadIdx.x;
  if (t < k) {
    float mu  = statS[t] * invn;
    float var = statS[k + t] * invn - mu * mu;
    float s = g[t] * rsqrtf(var + 1e-5f);
    scS[t] = s; shS[t] = bt[t] - mu * s;
  }
  __syncthreads();
  int i = blockIdx.x * 256 + t;
  if (i >= n) return;
  const float4* a = (const float4*)(A + (size_t)i * k);
  float acc = b[0];
  for (int j4 = 0; j4 < k / 4; j4++) {
    float4 x = a[j4];
    int c = j4 * 4;
    acc = fmaf(fmaxf(fmaf(x.x, scS[c],     shS[c]),     0.f), w[c],     acc);
    acc = fmaf(fmaxf(fmaf(x.y, scS[c + 1], shS[c + 1]), 0.f), w[c + 1], acc);
    acc = fmaf(fmaxf(fmaf(x.z, scS[c + 2], shS[c + 2]), 0.f), w[c + 2], acc);
    acc = fmaf(fmaxf(fmaf(x.w, scS[c + 3], shS[c + 3]), 0.f), w[c + 3], acc);
  }
  out[i] = acc;
}

extern "C" void kernel_launch(void* const* d_in, const int* in_sizes, int n_in,
                              void* d_out, int out_size, void* d_ws, size_t ws_size,
                              hipStream_t stream) {
  const float* inputs = (const float*)d_in[0];
  const int*   src    = (const int*)d_in[1];
  const int*   dst    = (const int*)d_in[2];
  const float* e1_W   = (const float*)d_in[3];
  const float* e1_b   = (const float*)d_in[4];
  const float* e_g    = (const float*)d_in[5];
  const float* e_bt   = (const float*)d_in[6];
  const float* e2_W   = (const float*)d_in[7];
  const float* e2_b   = (const float*)d_in[8];
  const float* gat_W  = (const float*)d_in[9];
  const float* gat_al = (const float*)d_in[10];
  const float* gat_ar = (const float*)d_in[11];
  const float* gat_b  = (const float*)d_in[12];
  const float* attn_p = (const float*)d_in[13];
  const float* m1_W   = (const float*)d_in[14];
  const float* m1_b   = (const float*)d_in[15];
  const float* m_g    = (const float*)d_in[16];
  const float* m_bt   = (const float*)d_in[17];
  const float* m2_W   = (const float*)d_in[18];
  const float* m2_b   = (const float*)d_in[19];
  const float* d1_W   = (const float*)d_in[20];
  const float* d1_b   = (const float*)d_in[21];
  const float* d_g    = (const float*)d_in[22];
  const float* d_bt   = (const float*)d_in[23];
  const float* d2_W   = (const float*)d_in[24];
  const float* d2_b   = (const float*)d_in[25];

  float* ws = (float*)d_ws;
  size_t o = 0;
  float*  h     = ws + o; o += (size_t)kN * kHID;
  float*  bufA  = ws + o; o += (size_t)kN * kHID;
  float*  vv    = ws + o; o += (size_t)kN * kHID;
  float*  elbuf = ws + o; o += (size_t)kN * 64;   // stride 64: shift-addressable
  float*  erbuf = ws + o; o += (size_t)kN * 64;
  __bf16* z     = (__bf16*)(ws + o); o += (size_t)kR * kN * kHID / 2;  // [r][N][128]
  __bf16* wt    = (__bf16*)(ws + o); o += 327680 / 2;
  // zero-region: degcur (6N ints) + stats (640 f32), one memset
  int* degcur   = (int*)(ws + o); o += (size_t)6 * kN;
  float* stats  = ws + o; o += 640;   // [e1:256][m1_l0:128][m1_l1:128][d1:128]
  int* rowptr   = (int*)(ws + o); o += (size_t)kR * (kN + 1);
  int* colidx   = (int*)(ws + o); o += (size_t)kR * kE;
  (void)ws_size; (void)in_sizes; (void)n_in; (void)out_size;

  int* deg    = degcur;
  int* cursor = degcur + 3 * kN;
  float* stat_e1 = stats;
  float* stat_m1[2] = {stats + 256, stats + 384};
  float* stat_d1 = stats + 512;

  // wt offsets (__bf16 elements; each matrix: hi[m][k] then lo[m][k])
  const long kWE1 = 0, kWE2 = 16384, kWZ = 49152;
  const long kWM1_0 = 245760, kWM1_1 = 262144, kWM2_0 = 278528, kWM2_1 = 294912, kWD1 = 311296;

  auto nb = [](long t) { return (int)((t + 255) / 256); };
  const dim3 gE(nb(kE), kR);
  const dim3 gM128((kN + 127) / 128, 2, 1);
  const dim3 gM64((kN + 127) / 128, 1, 1);
  const dim3 gMZ((kN + 127) / 128, 2, kR);
  const float invn = 1.0f / kN;
  float* F0 = nullptr; const float* cF0 = nullptr;

  // ---- CSR build + single zero memset ----
  hipMemsetAsync(degcur, 0, ((size_t)6 * kN + 640) * sizeof(int), stream);
  hist_kernel<<<gE, 256, 0, stream>>>(dst, deg);
  csr_scan_kernel<<<dim3(1, kR), 1024, 0, stream>>>(deg, rowptr);
  scatter_kernel<<<gE, 256, 0, stream>>>(src, dst, rowptr, cursor, colidx);

  // ---- weight prep ----
  WDescs wd;
  wd.d[0] = {e1_W, kWE1, kIN, kHID};
  wd.d[1] = {e2_W, kWE2, kHID, kHID};
  for (int i = 0; i < 6; i++) wd.d[2 + i] = {gat_W + (size_t)i * 16384, kWZ + (long)i * 32768, kHID, kHID};
  wd.d[8]  = {m1_W,        kWM1_0, kHID, kHD2};
  wd.d[9]  = {m1_W + 8192, kWM1_1, kHID, kHD2};
  wd.d[10] = {m2_W,        kWM2_0, kHD2, kHID};
  wd.d[11] = {m2_W + 8192, kWM2_1, kHD2, kHID};
  wd.d[12] = {d1_W,        kWD1,   kHID, kHD2};
  wprep_kernel<<<dim3(64, 13), 256, 0, stream>>>(wd, wt);

  // ---- embed MLP (skip=True) ----
  mgemm_kernel<<<gM128, 256, 0, stream>>>(inputs, wt + kWE1, e1_b, cF0, 0,
                                          cF0, cF0, cF0, invn, stat_e1, bufA, nullptr,
                                          cF0, cF0, F0, F0, kN, kIN, kHID, 0, 0, 3);
  mgemm_kernel<<<gM128, 256, 0, stream>>>(bufA, wt + kWE2, e2_b, bufA, 2,
                                          stat_e1, e_g, e_bt, invn, F0, h, nullptr,
                                          cF0, cF0, F0, F0, kN, kHID, kHID, 0, 0, 3);

  for (int l = 0; l < kL; l++) {
    // z projections: 2-pass split (output is bf16 anyway; el/er logits tolerate 2^-9)
    mgemm_kernel<<<gMZ, 256, 0, stream>>>(h, wt + kWZ + (long)l * 3 * 32768, cF0, cF0, 0,
                                          cF0, cF0, cF0, invn, F0, F0, z,
                                          gat_al + (size_t)l * kR * kHID,
                                          gat_ar + (size_t)l * kR * kHID, elbuf, erbuf,
                                          kN, kHID, kHID, 32768, (long)kN * kHID, 2);
    gat3_kernel<<<nb((long)kN * kH), 256, 0, stream>>>(rowptr, colidx, (const ushort*)z,
                                             elbuf, erbuf,
                                             attn_p + (size_t)l * kR * kHID,
                                             gat_b + (size_t)l * kR * kHID, vv);
    mgemm_kernel<<<gM64, 256, 0, stream>>>(vv, wt + (l ? kWM1_1 : kWM1_0),
                                           m1_b + (size_t)l * kHD2, cF0, 0,
                                           cF0, cF0, cF0, invn, stat_m1[l], bufA, nullptr,
                                           cF0, cF0, F0, F0, kN, kHID, kHD2, 0, 0, 3);
    mgemm_kernel<<<gM128, 256, 0, stream>>>(bufA, wt + (l ? kWM2_1 : kWM2_0),
                                            m2_b + (size_t)l * kHID, h, 1,
                                            stat_m1[l], m_g + (size_t)l * kHD2,
                                            m_bt + (size_t)l * kHD2, invn, F0, h, nullptr,
                                            cF0, cF0, F0, F0, kN, kHD2, kHID, 0, 0, 3);
  }

  // ---- decode MLP ----
  mgemm_kernel<<<gM64, 256, 0, stream>>>(h, wt + kWD1, d1_b, cF0, 0,
                                         cF0, cF0, cF0, invn, stat_d1, bufA, nullptr,
                                         cF0, cF0, F0, F0, kN, kHID, kHD2, 0, 0, 3);
  gemv_out_kernel<<<nb(kN), 256, 0, stream>>>(bufA, stat_d1, d_g, d_bt, invn,
                                              d2_W, d2_b, (float*)d_out, kN, kHD2);
}

// Round 14
// 333.068 us; speedup vs baseline: 1.0312x; 1.0312x over previous
//
#include <hip/hip_runtime.h>
#include <math.h>

// ---- problem constants ----
constexpr int kN   = 20000;
constexpr int kE   = 160000;
constexpr int kR   = 3;
constexpr int kL   = 2;
constexpr int kIN  = 64;
constexpr int kHID = 128;
constexpr int kH   = 16;
constexpr int kFH  = 8;
constexpr int kHD2 = 64;

typedef __bf16 bf16x8 __attribute__((ext_vector_type(8)));
typedef float  f32x4  __attribute__((ext_vector_type(4)));

__device__ __forceinline__ bf16x8 ldfrag(const __bf16* p) {
  return __builtin_bit_cast(bf16x8, *(const uint4*)p);
}
__device__ __forceinline__ f32x4 MF(bf16x8 a, bf16x8 b, f32x4 c) {
  return __builtin_amdgcn_mfma_f32_16x16x32_bf16(a, b, c, 0, 0, 0);
}

// split 8 f32 (optional BN+ReLU) into bf16 hi/lo fragments in-register
__device__ __forceinline__ void splitrow(const float* __restrict__ p, int koff,
                                         bool bn, const float* scS, const float* shS,
                                         bf16x8& hi, bf16x8& lo) {
  float4 xa = *(const float4*)(p + koff);
  float4 xb = *(const float4*)(p + koff + 4);
  float x[8] = {xa.x, xa.y, xa.z, xa.w, xb.x, xb.y, xb.z, xb.w};
  union { __bf16 b[8]; bf16x8 v; } uh, ul;
#pragma unroll
  for (int e = 0; e < 8; e++) {
    float y = x[e];
    if (bn) y = fmaxf(fmaf(y, scS[koff + e], shS[koff + e]), 0.f);
    __bf16 hb = (__bf16)y;
    uh.b[e] = hb;
    ul.b[e] = (__bf16)(y - (float)hb);
  }
  hi = uh.v; lo = ul.v;
}

// ============================================================================
// MFMA GEMM, bf16-split: C = [BN+ReLU?](A) @ W (+bias)(+res)
// BP=3: ah*bh + al*bh + ah*bl (~f32 precision) — h/MLP chain (35.8 KB LDS).
// BP=2: ah*bh + al*bh = A*W_hi (2^-9 rel err) — z-gemm: output is stored bf16
//       anyway; Bl LDS is ELIDED -> 18.7 KB LDS -> 8 blocks/CU (vs 4).
// el/er epilogue (z-gemm): elb/erb[row*64 + rel*16 + head] from exact f32 acc.
// ============================================================================
template <int BP>
__global__ __launch_bounds__(256) void mgemm_kernel(
    const float* __restrict__ A, const __bf16* __restrict__ WT,
    const float* __restrict__ bias, const float* __restrict__ resf, int resmode,
    const float* __restrict__ bnstat, const float* __restrict__ bng,
    const float* __restrict__ bnbt, float invn,
    float* __restrict__ statS,
    float* __restrict__ Cf, __bf16* __restrict__ Chi,
    const float* __restrict__ alb, const float* __restrict__ arb,
    float* __restrict__ elb, float* __restrict__ erb,
    int n, int k, int m, long wstride, long cstride) {
  __shared__ __bf16 Bh[64][136];                       // +8 pad -> conflict-free
  __shared__ __bf16 Bl[(BP == 3) ? 64 : 1][136];       // elided for BP=2
  __shared__ float scS[128], shS[128];
  const int t  = threadIdx.x;
  const int w  = t >> 6;
  const int l  = t & 63;
  const int lr = l & 15;
  const int lg = l >> 4;
  const int rb = blockIdx.x * 128 + w * 32;
  const int c0 = blockIdx.y * 64;
  const __bf16* Whi = WT + (size_t)blockIdx.z * wstride;
  const __bf16* Wlo = Whi + (size_t)k * m;
  if (Chi) Chi += (size_t)blockIdx.z * cstride;
  const float* al = alb ? alb + blockIdx.z * kHID : nullptr;
  const float* ar = arb ? arb + blockIdx.z * kHID : nullptr;
  if (elb) { elb += blockIdx.z * 16; erb += blockIdx.z * 16; }

  const bool bn = bnstat != nullptr;
  if (bn && t < k) {
    float mu  = bnstat[t] * invn;
    float var = bnstat[k + t] * invn - mu * mu;
    float s = bng[t] * rsqrtf(var + 1e-5f);
    scS[t] = s; shS[t] = bnbt[t] - mu * s;
  }
  const int kseg = k >> 3;
  for (int idx = t; idx < 64 * kseg; idx += 256) {
    int col = idx / kseg, seg = idx - col * kseg;
    *(uint4*)&Bh[col][seg * 8] = *(const uint4*)&Whi[(size_t)(c0 + col) * k + seg * 8];
    if constexpr (BP == 3)
      *(uint4*)&Bl[col][seg * 8] = *(const uint4*)&Wlo[(size_t)(c0 + col) * k + seg * 8];
  }
  __syncthreads();

  int r0 = rb + lr;      if (r0 > n - 1) r0 = n - 1;
  int r1 = rb + 16 + lr; if (r1 > n - 1) r1 = n - 1;
  f32x4 acc[2][4] = {};

  for (int ks = 0; ks < (k >> 5); ks++) {
    const int koff = ks * 32 + lg * 8;
    bf16x8 a0h, a0l, a1h, a1l;
    splitrow(&A[(size_t)r0 * k], koff, bn, scS, shS, a0h, a0l);
    splitrow(&A[(size_t)r1 * k], koff, bn, scS, shS, a1h, a1l);
#pragma unroll
    for (int j = 0; j < 4; j++) {
      bf16x8 bh = ldfrag(&Bh[j * 16 + lr][koff]);
      acc[0][j] = MF(a0h, bh, acc[0][j]);
      acc[0][j] = MF(a0l, bh, acc[0][j]);
      acc[1][j] = MF(a1h, bh, acc[1][j]);
      acc[1][j] = MF(a1l, bh, acc[1][j]);
      if constexpr (BP == 3) {
        bf16x8 bl = ldfrag(&Bl[j * 16 + lr][koff]);
        acc[0][j] = MF(a0h, bl, acc[0][j]);
        acc[1][j] = MF(a1h, bl, acc[1][j]);
      }
    }
  }

  // epilogue: D element (i,j,q) -> row rb+i*16+lg*4+q, col c0+j*16+lr
  float s[4] = {}, s2[4] = {};
#pragma unroll
  for (int i = 0; i < 2; i++) {
#pragma unroll
    for (int q = 0; q < 4; q++) {
      int row = rb + i * 16 + lg * 4 + q;
      bool ok = row < n;
#pragma unroll
      for (int j = 0; j < 4; j++) {
        int col = c0 + j * 16 + lr;
        float v = acc[i][j][q];
        if (bias) v += bias[col];
        size_t off = (size_t)row * m + col;
        if (ok) {
          if (resmode == 1) v += resf[off];
          else if (resmode == 2) v += fmaxf(fmaf(resf[off], scS[col], shS[col]), 0.f);
          if (Cf) Cf[off] = v;
          if (Chi) Chi[off] = (__bf16)v;
          s[j] += v; s2[j] += v * v;
        }
      }
    }
  }
  if (statS) {
    __syncthreads();
    float* red = (float*)&Bh[0][0];   // 512 floats scratch
#pragma unroll
    for (int j = 0; j < 4; j++) {
      float a = s[j], b = s2[j];
      a += __shfl_xor(a, 16, 64); a += __shfl_xor(a, 32, 64);
      b += __shfl_xor(b, 16, 64); b += __shfl_xor(b, 32, 64);
      if (lg == 0) { red[w * 64 + j * 16 + lr] = a; red[256 + w * 64 + j * 16 + lr] = b; }
    }
    __syncthreads();
    if (t < 64) {
      float a = red[t] + red[64 + t] + red[128 + t] + red[192 + t];
      float b = red[256 + t] + red[320 + t] + red[384 + t] + red[448 + t];
      atomicAdd(&statS[c0 + t], a);
      atomicAdd(&statS[m + c0 + t], b);
    }
  }
  if (al) {
#pragma unroll
    for (int i = 0; i < 2; i++) {
#pragma unroll
      for (int q = 0; q < 4; q++) {
        int row = rb + i * 16 + lg * 4 + q;
#pragma unroll
        for (int j = 0; j < 4; j++) {
          int col = c0 + j * 16 + lr;
          float zv = acc[i][j][q];
          float pl = zv * al[col];
          float pr = zv * ar[col];
          pl += __shfl_xor(pl, 1, 64); pl += __shfl_xor(pl, 2, 64); pl += __shfl_xor(pl, 4, 64);
          pr += __shfl_xor(pr, 1, 64); pr += __shfl_xor(pr, 2, 64); pr += __shfl_xor(pr, 4, 64);
          if ((lr & 7) == 0 && row < n) {
            int hd = col >> 3;   // global head 0..15
            elb[((size_t)row << 6) + hd] = pl;
            erb[((size_t)row << 6) + hd] = pr;
          }
        }
      }
    }
  }
}

// ---- combined prep: weight transpose+split (y<13) and dst histogram (y>=13) ----
struct WDesc { const float* src; long doff; int k, m; };
struct WDescs { WDesc d[13]; };
__global__ void prep_kernel(WDescs ds, __bf16* __restrict__ wt,
                            const int* __restrict__ dst, int* __restrict__ deg) {
  int y = blockIdx.y;
  if (y < 13) {
    WDesc dd = ds.d[y];
    int idx = blockIdx.x * 256 + threadIdx.x;
    if (idx >= dd.k * dd.m) return;
    int row = idx / dd.m, col = idx - row * dd.m;
    float v = dd.src[idx];
    __bf16 hb = (__bf16)v;
    __bf16 lb = (__bf16)(v - (float)hb);
    wt[dd.doff + (size_t)col * dd.k + row] = hb;
    wt[dd.doff + (size_t)dd.k * dd.m + (size_t)col * dd.k + row] = lb;
  } else {
    int r = y - 13;
    int e = blockIdx.x * 256 + threadIdx.x;
    if (e < kE) atomicAdd(&deg[r * kN + dst[r * kE + e]], 1);
  }
}

__global__ __launch_bounds__(1024) void csr_scan_kernel(const int* __restrict__ deg,
                                                        int* __restrict__ rowptr) {
  const int r = blockIdx.y;
  const int* dg = deg + r * kN;
  int* rp = rowptr + r * (kN + 1);
  const int t = threadIdx.x;
  constexpr int C = (kN + 1023) / 1024;   // 20
  const int base = t * C;
  int sum = 0;
#pragma unroll
  for (int i = 0; i < C; i++) {
    int j = base + i;
    if (j < kN) sum += dg[j];
  }
  __shared__ int warpTot[16];
  int lane = t & 63, wid = t >> 6;
  int v = sum;
  for (int off = 1; off < 64; off <<= 1) {
    int y = __shfl_up(v, off, 64);
    if (lane >= off) v += y;
  }
  if (lane == 63) warpTot[wid] = v;
  __syncthreads();
  int wadd = 0;
#pragma unroll
  for (int i = 0; i < 16; i++) if (i < wid) wadd += warpTot[i];
  int run = wadd + v - sum;
#pragma unroll
  for (int i = 0; i < C; i++) {
    int j = base + i;
    if (j < kN) { rp[j] = run; run += dg[j]; }
  }
  if (t == 1023) rp[kN] = run;
}

__global__ void scatter_kernel(const int* __restrict__ src, const int* __restrict__ dst,
                               const int* __restrict__ rowptr, int* __restrict__ cursor,
                               int* __restrict__ col) {
  int r = blockIdx.y;
  int e = blockIdx.x * 256 + threadIdx.x;
  if (e < kE) {
    int d = dst[r * kE + e];
    int p = atomicAdd(&cursor[r * kN + d], 1);
    col[r * kE + rowptr[r * (kN + 1) + d] + p] = src[r * kE + e];
  }
}

// ---- fused relation-softmax + edge softmax + aggregation ----
// thread per (dst, head); masked 8-wide batched edge loop: every edge load
// issues in an 8-deep batch (OOB lanes clamp to end-1 and get ex=0 -> exact).
__global__ void gat3_kernel(const int* __restrict__ rowptr, const int* __restrict__ colidx,
                            const ushort* __restrict__ z, const float* __restrict__ elb,
                            const float* __restrict__ erb,
                            const float* __restrict__ attn_pl, const float* __restrict__ gat_bl,
                            float* __restrict__ vv) {
  __shared__ float wsmS[kR * kHID], cvecS[kHID];
  int t = threadIdx.x;
  if (t < kHID) {
    float p0 = attn_pl[t], p1 = attn_pl[kHID + t], p2 = attn_pl[2 * kHID + t];
    float mx = fmaxf(p0, fmaxf(p1, p2));
    float e0 = __expf(p0 - mx), e1 = __expf(p1 - mx), e2 = __expf(p2 - mx);
    float si = 1.f / (e0 + e1 + e2);
    wsmS[t] = e0 * si; wsmS[kHID + t] = e1 * si; wsmS[2 * kHID + t] = e2 * si;
    cvecS[t] = (e0 * gat_bl[t] + e1 * gat_bl[kHID + t] + e2 * gat_bl[2 * kHID + t]) * si;
  }
  __syncthreads();
  int idx = blockIdx.x * 256 + t;
  if (idx >= kN * kH) return;
  int d = idx >> 4, hh = idx & 15;
  const int fo = hh << 3;
  float out[kFH];
#pragma unroll
  for (int f = 0; f < kFH; f++) out[f] = cvecS[fo + f];
  for (int r = 0; r < kR; r++) {
    const int* rp = rowptr + r * (kN + 1);
    const int* ci = colidx + (size_t)r * kE;
    const ushort* zr = z + (size_t)r * kN * kHID;
    const int ro = r * 16 + hh;
    float erd = erb[((size_t)d << 6) + ro];
    int beg = rp[d], end = rp[d + 1];
    float s = 0.f;
    float acc[kFH] = {};
    for (int p = beg; p < end; p += 8) {
      int q[8]; float ev[8]; uint4 zz[8];
#pragma unroll
      for (int u = 0; u < 8; u++) {
        int pp = p + u;
        q[u] = ci[pp < end ? pp : end - 1];
      }
#pragma unroll
      for (int u = 0; u < 8; u++) ev[u] = elb[((size_t)q[u] << 6) + ro];
#pragma unroll
      for (int u = 0; u < 8; u++) zz[u] = *(const uint4*)(zr + ((size_t)q[u] << 7) + fo);
#pragma unroll
      for (int u = 0; u < 8; u++) {
        float v = ev[u] + erd;
        v = v > 0.f ? v : 0.2f * v;
        float ex = (p + u < end) ? __expf(v) : 0.f;   // logits O(0.1): no overflow
        s += ex;
        acc[0] = fmaf(ex, __uint_as_float(zz[u].x << 16),         acc[0]);
        acc[1] = fmaf(ex, __uint_as_float(zz[u].x & 0xffff0000u), acc[1]);
        acc[2] = fmaf(ex, __uint_as_float(zz[u].y << 16),         acc[2]);
        acc[3] = fmaf(ex, __uint_as_float(zz[u].y & 0xffff0000u), acc[3]);
        acc[4] = fmaf(ex, __uint_as_float(zz[u].z << 16),         acc[4]);
        acc[5] = fmaf(ex, __uint_as_float(zz[u].z & 0xffff0000u), acc[5]);
        acc[6] = fmaf(ex, __uint_as_float(zz[u].w << 16),         acc[6]);
        acc[7] = fmaf(ex, __uint_as_float(zz[u].w & 0xffff0000u), acc[7]);
      }
    }
    float inv = s > 0.f ? 1.f / s : 0.f;
    const float* wp = wsmS + r * kHID + fo;
#pragma unroll
    for (int f = 0; f < kFH; f++) out[f] = fmaf(wp[f] * inv, acc[f], out[f]);
  }
  float4* vp = (float4*)(vv + ((size_t)d << 7) + fo);
  vp[0] = make_float4(out[0], out[1], out[2], out[3]);
  vp[1] = make_float4(out[4], out[5], out[6], out[7]);
}

// ---- final gemv: BN fold from raw stats + BN+ReLU + dot, all fused ----
__global__ void gemv_out_kernel(const float* __restrict__ A, const float* __restrict__ statS,
                                const float* __restrict__ g, const float* __restrict__ bt,
                                float invn, const float* __restrict__ w,
                                const float* __restrict__ b, float* __restrict__ out,
                                int n, int k) {
  __shared__ float scS[kHD2], shS[kHD2];
  int t = threadIdx.x;
  if (t < k) {
    float mu  = statS[t] * invn;
    float var = statS[k + t] * invn - mu * mu;
    float s = g[t] * rsqrtf(var + 1e-5f);
    scS[t] = s; shS[t] = bt[t] - mu * s;
  }
  __syncthreads();
  int i = blockIdx.x * 256 + t;
  if (i >= n) return;
  const float4* a = (const float4*)(A + (size_t)i * k);
  float acc = b[0];
  for (int j4 = 0; j4 < k / 4; j4++) {
    float4 x = a[j4];
    int c = j4 * 4;
    acc = fmaf(fmaxf(fmaf(x.x, scS[c],     shS[c]),     0.f), w[c],     acc);
    acc = fmaf(fmaxf(fmaf(x.y, scS[c + 1], shS[c + 1]), 0.f), w[c + 1], acc);
    acc = fmaf(fmaxf(fmaf(x.z, scS[c + 2], shS[c + 2]), 0.f), w[c + 2], acc);
    acc = fmaf(fmaxf(fmaf(x.w, scS[c + 3], shS[c + 3]), 0.f), w[c + 3], acc);
  }
  out[i] = acc;
}

extern "C" void kernel_launch(void* const* d_in, const int* in_sizes, int n_in,
                              void* d_out, int out_size, void* d_ws, size_t ws_size,
                              hipStream_t stream) {
  const float* inputs = (const float*)d_in[0];
  const int*   src    = (const int*)d_in[1];
  const int*   dst    = (const int*)d_in[2];
  const float* e1_W   = (const float*)d_in[3];
  const float* e1_b   = (const float*)d_in[4];
  const float* e_g    = (const float*)d_in[5];
  const float* e_bt   = (const float*)d_in[6];
  const float* e2_W   = (const float*)d_in[7];
  const float* e2_b   = (const float*)d_in[8];
  const float* gat_W  = (const float*)d_in[9];
  const float* gat_al = (const float*)d_in[10];
  const float* gat_ar = (const float*)d_in[11];
  const float* gat_b  = (const float*)d_in[12];
  const float* attn_p = (const float*)d_in[13];
  const float* m1_W   = (const float*)d_in[14];
  const float* m1_b   = (const float*)d_in[15];
  const float* m_g    = (const float*)d_in[16];
  const float* m_bt   = (const float*)d_in[17];
  const float* m2_W   = (const float*)d_in[18];
  const float* m2_b   = (const float*)d_in[19];
  const float* d1_W   = (const float*)d_in[20];
  const float* d1_b   = (const float*)d_in[21];
  const float* d_g    = (const float*)d_in[22];
  const float* d_bt   = (const float*)d_in[23];
  const float* d2_W   = (const float*)d_in[24];
  const float* d2_b   = (const float*)d_in[25];

  float* ws = (float*)d_ws;
  size_t o = 0;
  float*  h     = ws + o; o += (size_t)kN * kHID;
  float*  bufA  = ws + o; o += (size_t)kN * kHID;
  float*  vv    = ws + o; o += (size_t)kN * kHID;
  float*  elbuf = ws + o; o += (size_t)kN * 64;   // stride 64: shift-addressable
  float*  erbuf = ws + o; o += (size_t)kN * 64;
  __bf16* z     = (__bf16*)(ws + o); o += (size_t)kR * kN * kHID / 2;  // [r][N][128]
  __bf16* wt    = (__bf16*)(ws + o); o += 327680 / 2;
  // zero-region: degcur (6N ints) + stats (640 f32), one memset
  int* degcur   = (int*)(ws + o); o += (size_t)6 * kN;
  float* stats  = ws + o; o += 640;   // [e1:256][m1_l0:128][m1_l1:128][d1:128]
  int* rowptr   = (int*)(ws + o); o += (size_t)kR * (kN + 1);
  int* colidx   = (int*)(ws + o); o += (size_t)kR * kE;
  (void)ws_size; (void)in_sizes; (void)n_in; (void)out_size;

  int* deg    = degcur;
  int* cursor = degcur + 3 * kN;
  float* stat_e1 = stats;
  float* stat_m1[2] = {stats + 256, stats + 384};
  float* stat_d1 = stats + 512;

  // wt offsets (__bf16 elements; each matrix: hi[m][k] then lo[m][k])
  const long kWE1 = 0, kWE2 = 16384, kWZ = 49152;
  const long kWM1_0 = 245760, kWM1_1 = 262144, kWM2_0 = 278528, kWM2_1 = 294912, kWD1 = 311296;

  auto nb = [](long t) { return (int)((t + 255) / 256); };
  const dim3 gE(nb(kE), kR);
  const dim3 gP(nb(kE), 16);                 // prep: y<13 wprep, y>=13 hist
  const dim3 gM128((kN + 127) / 128, 2, 1);
  const dim3 gM64((kN + 127) / 128, 1, 1);
  const dim3 gMZ((kN + 127) / 128, 2, kR);
  const float invn = 1.0f / kN;
  float* F0 = nullptr; const float* cF0 = nullptr;

  // ---- prep: zero memset, then combined wprep+hist, scan, scatter ----
  WDescs wd;
  wd.d[0] = {e1_W, kWE1, kIN, kHID};
  wd.d[1] = {e2_W, kWE2, kHID, kHID};
  for (int i = 0; i < 6; i++) wd.d[2 + i] = {gat_W + (size_t)i * 16384, kWZ + (long)i * 32768, kHID, kHID};
  wd.d[8]  = {m1_W,        kWM1_0, kHID, kHD2};
  wd.d[9]  = {m1_W + 8192, kWM1_1, kHID, kHD2};
  wd.d[10] = {m2_W,        kWM2_0, kHD2, kHID};
  wd.d[11] = {m2_W + 8192, kWM2_1, kHD2, kHID};
  wd.d[12] = {d1_W,        kWD1,   kHID, kHD2};
  hipMemsetAsync(degcur, 0, ((size_t)6 * kN + 640) * sizeof(int), stream);
  prep_kernel<<<gP, 256, 0, stream>>>(wd, wt, dst, deg);
  csr_scan_kernel<<<dim3(1, kR), 1024, 0, stream>>>(deg, rowptr);
  scatter_kernel<<<gE, 256, 0, stream>>>(src, dst, rowptr, cursor, colidx);

  // ---- embed MLP (skip=True) ----
  mgemm_kernel<3><<<gM128, 256, 0, stream>>>(inputs, wt + kWE1, e1_b, cF0, 0,
                                          cF0, cF0, cF0, invn, stat_e1, bufA, nullptr,
                                          cF0, cF0, F0, F0, kN, kIN, kHID, 0, 0);
  mgemm_kernel<3><<<gM128, 256, 0, stream>>>(bufA, wt + kWE2, e2_b, bufA, 2,
                                          stat_e1, e_g, e_bt, invn, F0, h, nullptr,
                                          cF0, cF0, F0, F0, kN, kHID, kHID, 0, 0);

  for (int l = 0; l < kL; l++) {
    // z projections: 2-pass split (output stored bf16; r13 evidence absmax 0.0039)
    // with Bl LDS elided -> 8 blocks/CU for better gather/load latency hiding
    mgemm_kernel<2><<<gMZ, 256, 0, stream>>>(h, wt + kWZ + (long)l * 3 * 32768, cF0, cF0, 0,
                                          cF0, cF0, cF0, invn, F0, F0, z,
                                          gat_al + (size_t)l * kR * kHID,
                                          gat_ar + (size_t)l * kR * kHID, elbuf, erbuf,
                                          kN, kHID, kHID, 32768, (long)kN * kHID);
    gat3_kernel<<<nb((long)kN * kH), 256, 0, stream>>>(rowptr, colidx, (const ushort*)z,
                                             elbuf, erbuf,
                                             attn_p + (size_t)l * kR * kHID,
                                             gat_b + (size_t)l * kR * kHID, vv);
    mgemm_kernel<3><<<gM64, 256, 0, stream>>>(vv, wt + (l ? kWM1_1 : kWM1_0),
                                           m1_b + (size_t)l * kHD2, cF0, 0,
                                           cF0, cF0, cF0, invn, stat_m1[l], bufA, nullptr,
                                           cF0, cF0, F0, F0, kN, kHID, kHD2, 0, 0);
    mgemm_kernel<3><<<gM128, 256, 0, stream>>>(bufA, wt + (l ? kWM2_1 : kWM2_0),
                                            m2_b + (size_t)l * kHID, h, 1,
                                            stat_m1[l], m_g + (size_t)l * kHD2,
                                            m_bt + (size_t)l * kHD2, invn, F0, h, nullptr,
                                            cF0, cF0, F0, F0, kN, kHD2, kHID, 0, 0);
  }

  // ---- decode MLP ----
  mgemm_kernel<3><<<gM64, 256, 0, stream>>>(h, wt + kWD1, d1_b, cF0, 0,
                                         cF0, cF0, cF0, invn, stat_d1, bufA, nullptr,
                                         cF0, cF0, F0, F0, kN, kHID, kHD2, 0, 0);
  gemv_out_kernel<<<nb(kN), 256, 0, stream>>>(bufA, stat_d1, d_g, d_bt, invn,
                                              d2_W, d2_b, (float*)d_out, kN, kHD2);
}

// Round 15
// 305.652 us; speedup vs baseline: 1.1237x; 1.0897x over previous
//
#include <hip/hip_runtime.h>
#include <math.h>

// ---- problem constants ----
constexpr int kN   = 20000;
constexpr int kE   = 160000;
constexpr int kR   = 3;
constexpr int kL   = 2;
constexpr int kIN  = 64;
constexpr int kHID = 128;
constexpr int kH   = 16;
constexpr int kFH  = 8;
constexpr int kHD2 = 64;

typedef __bf16 bf16x8 __attribute__((ext_vector_type(8)));
typedef float  f32x4  __attribute__((ext_vector_type(4)));

__device__ __forceinline__ bf16x8 ldfrag(const __bf16* p) {
  return __builtin_bit_cast(bf16x8, *(const uint4*)p);
}
__device__ __forceinline__ f32x4 MF(bf16x8 a, bf16x8 b, f32x4 c) {
  return __builtin_amdgcn_mfma_f32_16x16x32_bf16(a, b, c, 0, 0, 0);
}

// split 8 f32 (optional BN+ReLU) into bf16 hi/lo fragments in-register
__device__ __forceinline__ void splitrow(const float* __restrict__ p, int koff,
                                         bool bn, const float* scS, const float* shS,
                                         bf16x8& hi, bf16x8& lo) {
  float4 xa = *(const float4*)(p + koff);
  float4 xb = *(const float4*)(p + koff + 4);
  float x[8] = {xa.x, xa.y, xa.z, xa.w, xb.x, xb.y, xb.z, xb.w};
  union { __bf16 b[8]; bf16x8 v; } uh, ul;
#pragma unroll
  for (int e = 0; e < 8; e++) {
    float y = x[e];
    if (bn) y = fmaxf(fmaf(y, scS[koff + e], shS[koff + e]), 0.f);
    __bf16 hb = (__bf16)y;
    uh.b[e] = hb;
    ul.b[e] = (__bf16)(y - (float)hb);
  }
  hi = uh.v; lo = ul.v;
}

// ============================================================================
// MFMA GEMM, bf16-split: C = [BN+ReLU?](A) @ W (+bias)(+res)
// BM=64 tile (4 waves x 16 rows, acc[4]): 2x block count vs BM=128 ->
//   626 blocks (m=128) / 1878 (z-gemm) on 256 CUs for latency hiding.
// BP=3: ah*bh + al*bh + ah*bl (~f32 precision) — h/MLP chain.
// BP=2: ah*bh + al*bh = A*W_hi (2^-9 rel err) — z-gemm (output stored bf16);
//       Bl LDS elided -> 18.7 KB -> 8 blocks/CU.
// el/er epilogue (z-gemm): elb/erb[row*64 + rel*16 + head] from exact f32 acc.
// ============================================================================
template <int BP>
__global__ __launch_bounds__(256) void mgemm_kernel(
    const float* __restrict__ A, const __bf16* __restrict__ WT,
    const float* __restrict__ bias, const float* __restrict__ resf, int resmode,
    const float* __restrict__ bnstat, const float* __restrict__ bng,
    const float* __restrict__ bnbt, float invn,
    float* __restrict__ statS,
    float* __restrict__ Cf, __bf16* __restrict__ Chi,
    const float* __restrict__ alb, const float* __restrict__ arb,
    float* __restrict__ elb, float* __restrict__ erb,
    int n, int k, int m, long wstride, long cstride) {
  __shared__ __bf16 Bh[64][136];                       // +8 pad -> conflict-free
  __shared__ __bf16 Bl[(BP == 3) ? 64 : 1][136];       // elided for BP=2
  __shared__ float scS[128], shS[128];
  const int t  = threadIdx.x;
  const int w  = t >> 6;
  const int l  = t & 63;
  const int lr = l & 15;
  const int lg = l >> 4;
  const int rb = blockIdx.x * 64 + w * 16;             // BM=64: wave owns 16 rows
  const int c0 = blockIdx.y * 64;
  const __bf16* Whi = WT + (size_t)blockIdx.z * wstride;
  const __bf16* Wlo = Whi + (size_t)k * m;
  if (Chi) Chi += (size_t)blockIdx.z * cstride;
  const float* al = alb ? alb + blockIdx.z * kHID : nullptr;
  const float* ar = arb ? arb + blockIdx.z * kHID : nullptr;
  if (elb) { elb += blockIdx.z * 16; erb += blockIdx.z * 16; }

  const bool bn = bnstat != nullptr;
  if (bn && t < k) {
    float mu  = bnstat[t] * invn;
    float var = bnstat[k + t] * invn - mu * mu;
    float s = bng[t] * rsqrtf(var + 1e-5f);
    scS[t] = s; shS[t] = bnbt[t] - mu * s;
  }
  const int kseg = k >> 3;
  for (int idx = t; idx < 64 * kseg; idx += 256) {
    int col = idx / kseg, seg = idx - col * kseg;
    *(uint4*)&Bh[col][seg * 8] = *(const uint4*)&Whi[(size_t)(c0 + col) * k + seg * 8];
    if constexpr (BP == 3)
      *(uint4*)&Bl[col][seg * 8] = *(const uint4*)&Wlo[(size_t)(c0 + col) * k + seg * 8];
  }
  __syncthreads();

  int r0 = rb + lr; if (r0 > n - 1) r0 = n - 1;
  f32x4 acc[4] = {};

  for (int ks = 0; ks < (k >> 5); ks++) {
    const int koff = ks * 32 + lg * 8;
    bf16x8 a0h, a0l;
    splitrow(&A[(size_t)r0 * k], koff, bn, scS, shS, a0h, a0l);
#pragma unroll
    for (int j = 0; j < 4; j++) {
      bf16x8 bh = ldfrag(&Bh[j * 16 + lr][koff]);
      acc[j] = MF(a0h, bh, acc[j]);
      acc[j] = MF(a0l, bh, acc[j]);
      if constexpr (BP == 3) {
        bf16x8 bl = ldfrag(&Bl[j * 16 + lr][koff]);
        acc[j] = MF(a0h, bl, acc[j]);
      }
    }
  }

  // epilogue: D element (j,q) -> row rb+lg*4+q, col c0+j*16+lr
  float s[4] = {}, s2[4] = {};
#pragma unroll
  for (int q = 0; q < 4; q++) {
    int row = rb + lg * 4 + q;
    bool ok = row < n;
#pragma unroll
    for (int j = 0; j < 4; j++) {
      int col = c0 + j * 16 + lr;
      float v = acc[j][q];
      if (bias) v += bias[col];
      size_t off = (size_t)row * m + col;
      if (ok) {
        if (resmode == 1) v += resf[off];
        else if (resmode == 2) v += fmaxf(fmaf(resf[off], scS[col], shS[col]), 0.f);
        if (Cf) Cf[off] = v;
        if (Chi) Chi[off] = (__bf16)v;
        s[j] += v; s2[j] += v * v;
      }
    }
  }
  if (statS) {
    __syncthreads();
    float* red = (float*)&Bh[0][0];   // 512 floats scratch
#pragma unroll
    for (int j = 0; j < 4; j++) {
      float a = s[j], b = s2[j];
      a += __shfl_xor(a, 16, 64); a += __shfl_xor(a, 32, 64);
      b += __shfl_xor(b, 16, 64); b += __shfl_xor(b, 32, 64);
      if (lg == 0) { red[w * 64 + j * 16 + lr] = a; red[256 + w * 64 + j * 16 + lr] = b; }
    }
    __syncthreads();
    if (t < 64) {
      float a = red[t] + red[64 + t] + red[128 + t] + red[192 + t];
      float b = red[256 + t] + red[320 + t] + red[384 + t] + red[448 + t];
      atomicAdd(&statS[c0 + t], a);
      atomicAdd(&statS[m + c0 + t], b);
    }
  }
  if (al) {
#pragma unroll
    for (int q = 0; q < 4; q++) {
      int row = rb + lg * 4 + q;
#pragma unroll
      for (int j = 0; j < 4; j++) {
        int col = c0 + j * 16 + lr;
        float zv = acc[j][q];
        float pl = zv * al[col];
        float pr = zv * ar[col];
        pl += __shfl_xor(pl, 1, 64); pl += __shfl_xor(pl, 2, 64); pl += __shfl_xor(pl, 4, 64);
        pr += __shfl_xor(pr, 1, 64); pr += __shfl_xor(pr, 2, 64); pr += __shfl_xor(pr, 4, 64);
        if ((lr & 7) == 0 && row < n) {
          int hd = col >> 3;   // global head 0..15
          elb[((size_t)row << 6) + hd] = pl;
          erb[((size_t)row << 6) + hd] = pr;
        }
      }
    }
  }
}

// ---- combined prep: weight transpose+split (y<13) and dst histogram (y>=13) ----
struct WDesc { const float* src; long doff; int k, m; };
struct WDescs { WDesc d[13]; };
__global__ void prep_kernel(WDescs ds, __bf16* __restrict__ wt,
                            const int* __restrict__ dst, int* __restrict__ deg) {
  int y = blockIdx.y;
  if (y < 13) {
    WDesc dd = ds.d[y];
    int idx = blockIdx.x * 256 + threadIdx.x;
    if (idx >= dd.k * dd.m) return;
    int row = idx / dd.m, col = idx - row * dd.m;
    float v = dd.src[idx];
    __bf16 hb = (__bf16)v;
    __bf16 lb = (__bf16)(v - (float)hb);
    wt[dd.doff + (size_t)col * dd.k + row] = hb;
    wt[dd.doff + (size_t)dd.k * dd.m + (size_t)col * dd.k + row] = lb;
  } else {
    int r = y - 13;
    int e = blockIdx.x * 256 + threadIdx.x;
    if (e < kE) atomicAdd(&deg[r * kN + dst[r * kE + e]], 1);
  }
}

__global__ __launch_bounds__(1024) void csr_scan_kernel(const int* __restrict__ deg,
                                                        int* __restrict__ rowptr) {
  const int r = blockIdx.y;
  const int* dg = deg + r * kN;
  int* rp = rowptr + r * (kN + 1);
  const int t = threadIdx.x;
  constexpr int C = (kN + 1023) / 1024;   // 20
  const int base = t * C;
  int sum = 0;
#pragma unroll
  for (int i = 0; i < C; i++) {
    int j = base + i;
    if (j < kN) sum += dg[j];
  }
  __shared__ int warpTot[16];
  int lane = t & 63, wid = t >> 6;
  int v = sum;
  for (int off = 1; off < 64; off <<= 1) {
    int y = __shfl_up(v, off, 64);
    if (lane >= off) v += y;
  }
  if (lane == 63) warpTot[wid] = v;
  __syncthreads();
  int wadd = 0;
#pragma unroll
  for (int i = 0; i < 16; i++) if (i < wid) wadd += warpTot[i];
  int run = wadd + v - sum;
#pragma unroll
  for (int i = 0; i < C; i++) {
    int j = base + i;
    if (j < kN) { rp[j] = run; run += dg[j]; }
  }
  if (t == 1023) rp[kN] = run;
}

__global__ void scatter_kernel(const int* __restrict__ src, const int* __restrict__ dst,
                               const int* __restrict__ rowptr, int* __restrict__ cursor,
                               int* __restrict__ col) {
  int r = blockIdx.y;
  int e = blockIdx.x * 256 + threadIdx.x;
  if (e < kE) {
    int d = dst[r * kE + e];
    int p = atomicAdd(&cursor[r * kN + d], 1);
    col[r * kE + rowptr[r * (kN + 1) + d] + p] = src[r * kE + e];
  }
}

// ---- fused relation-softmax + edge softmax + aggregation ----
// thread per (dst, head); masked 8-wide batched edge loop: every edge load
// issues in an 8-deep batch (OOB lanes clamp to end-1 and get ex=0 -> exact).
__global__ void gat3_kernel(const int* __restrict__ rowptr, const int* __restrict__ colidx,
                            const ushort* __restrict__ z, const float* __restrict__ elb,
                            const float* __restrict__ erb,
                            const float* __restrict__ attn_pl, const float* __restrict__ gat_bl,
                            float* __restrict__ vv) {
  __shared__ float wsmS[kR * kHID], cvecS[kHID];
  int t = threadIdx.x;
  if (t < kHID) {
    float p0 = attn_pl[t], p1 = attn_pl[kHID + t], p2 = attn_pl[2 * kHID + t];
    float mx = fmaxf(p0, fmaxf(p1, p2));
    float e0 = __expf(p0 - mx), e1 = __expf(p1 - mx), e2 = __expf(p2 - mx);
    float si = 1.f / (e0 + e1 + e2);
    wsmS[t] = e0 * si; wsmS[kHID + t] = e1 * si; wsmS[2 * kHID + t] = e2 * si;
    cvecS[t] = (e0 * gat_bl[t] + e1 * gat_bl[kHID + t] + e2 * gat_bl[2 * kHID + t]) * si;
  }
  __syncthreads();
  int idx = blockIdx.x * 256 + t;
  if (idx >= kN * kH) return;
  int d = idx >> 4, hh = idx & 15;
  const int fo = hh << 3;
  float out[kFH];
#pragma unroll
  for (int f = 0; f < kFH; f++) out[f] = cvecS[fo + f];
  for (int r = 0; r < kR; r++) {
    const int* rp = rowptr + r * (kN + 1);
    const int* ci = colidx + (size_t)r * kE;
    const ushort* zr = z + (size_t)r * kN * kHID;
    const int ro = r * 16 + hh;
    float erd = erb[((size_t)d << 6) + ro];
    int beg = rp[d], end = rp[d + 1];
    float s = 0.f;
    float acc[kFH] = {};
    for (int p = beg; p < end; p += 8) {
      int q[8]; float ev[8]; uint4 zz[8];
#pragma unroll
      for (int u = 0; u < 8; u++) {
        int pp = p + u;
        q[u] = ci[pp < end ? pp : end - 1];
      }
#pragma unroll
      for (int u = 0; u < 8; u++) ev[u] = elb[((size_t)q[u] << 6) + ro];
#pragma unroll
      for (int u = 0; u < 8; u++) zz[u] = *(const uint4*)(zr + ((size_t)q[u] << 7) + fo);
#pragma unroll
      for (int u = 0; u < 8; u++) {
        float v = ev[u] + erd;
        v = v > 0.f ? v : 0.2f * v;
        float ex = (p + u < end) ? __expf(v) : 0.f;   // logits O(0.1): no overflow
        s += ex;
        acc[0] = fmaf(ex, __uint_as_float(zz[u].x << 16),         acc[0]);
        acc[1] = fmaf(ex, __uint_as_float(zz[u].x & 0xffff0000u), acc[1]);
        acc[2] = fmaf(ex, __uint_as_float(zz[u].y << 16),         acc[2]);
        acc[3] = fmaf(ex, __uint_as_float(zz[u].y & 0xffff0000u), acc[3]);
        acc[4] = fmaf(ex, __uint_as_float(zz[u].z << 16),         acc[4]);
        acc[5] = fmaf(ex, __uint_as_float(zz[u].z & 0xffff0000u), acc[5]);
        acc[6] = fmaf(ex, __uint_as_float(zz[u].w << 16),         acc[6]);
        acc[7] = fmaf(ex, __uint_as_float(zz[u].w & 0xffff0000u), acc[7]);
      }
    }
    float inv = s > 0.f ? 1.f / s : 0.f;
    const float* wp = wsmS + r * kHID + fo;
#pragma unroll
    for (int f = 0; f < kFH; f++) out[f] = fmaf(wp[f] * inv, acc[f], out[f]);
  }
  float4* vp = (float4*)(vv + ((size_t)d << 7) + fo);
  vp[0] = make_float4(out[0], out[1], out[2], out[3]);
  vp[1] = make_float4(out[4], out[5], out[6], out[7]);
}

// ---- final gemv: BN fold from raw stats + BN+ReLU + dot, all fused ----
__global__ void gemv_out_kernel(const float* __restrict__ A, const float* __restrict__ statS,
                                const float* __restrict__ g, const float* __restrict__ bt,
                                float invn, const float* __restrict__ w,
                                const float* __restrict__ b, float* __restrict__ out,
                                int n, int k) {
  __shared__ float scS[kHD2], shS[kHD2];
  int t = threadIdx.x;
  if (t < k) {
    float mu  = statS[t] * invn;
    float var = statS[k + t] * invn - mu * mu;
    float s = g[t] * rsqrtf(var + 1e-5f);
    scS[t] = s; shS[t] = bt[t] - mu * s;
  }
  __syncthreads();
  int i = blockIdx.x * 256 + t;
  if (i >= n) return;
  const float4* a = (const float4*)(A + (size_t)i * k);
  float acc = b[0];
  for (int j4 = 0; j4 < k / 4; j4++) {
    float4 x = a[j4];
    int c = j4 * 4;
    acc = fmaf(fmaxf(fmaf(x.x, scS[c],     shS[c]),     0.f), w[c],     acc);
    acc = fmaf(fmaxf(fmaf(x.y, scS[c + 1], shS[c + 1]), 0.f), w[c + 1], acc);
    acc = fmaf(fmaxf(fmaf(x.z, scS[c + 2], shS[c + 2]), 0.f), w[c + 2], acc);
    acc = fmaf(fmaxf(fmaf(x.w, scS[c + 3], shS[c + 3]), 0.f), w[c + 3], acc);
  }
  out[i] = acc;
}

extern "C" void kernel_launch(void* const* d_in, const int* in_sizes, int n_in,
                              void* d_out, int out_size, void* d_ws, size_t ws_size,
                              hipStream_t stream) {
  const float* inputs = (const float*)d_in[0];
  const int*   src    = (const int*)d_in[1];
  const int*   dst    = (const int*)d_in[2];
  const float* e1_W   = (const float*)d_in[3];
  const float* e1_b   = (const float*)d_in[4];
  const float* e_g    = (const float*)d_in[5];
  const float* e_bt   = (const float*)d_in[6];
  const float* e2_W   = (const float*)d_in[7];
  const float* e2_b   = (const float*)d_in[8];
  const float* gat_W  = (const float*)d_in[9];
  const float* gat_al = (const float*)d_in[10];
  const float* gat_ar = (const float*)d_in[11];
  const float* gat_b  = (const float*)d_in[12];
  const float* attn_p = (const float*)d_in[13];
  const float* m1_W   = (const float*)d_in[14];
  const float* m1_b   = (const float*)d_in[15];
  const float* m_g    = (const float*)d_in[16];
  const float* m_bt   = (const float*)d_in[17];
  const float* m2_W   = (const float*)d_in[18];
  const float* m2_b   = (const float*)d_in[19];
  const float* d1_W   = (const float*)d_in[20];
  const float* d1_b   = (const float*)d_in[21];
  const float* d_g    = (const float*)d_in[22];
  const float* d_bt   = (const float*)d_in[23];
  const float* d2_W   = (const float*)d_in[24];
  const float* d2_b   = (const float*)d_in[25];

  float* ws = (float*)d_ws;
  size_t o = 0;
  float*  h     = ws + o; o += (size_t)kN * kHID;
  float*  bufA  = ws + o; o += (size_t)kN * kHID;
  float*  vv    = ws + o; o += (size_t)kN * kHID;
  float*  elbuf = ws + o; o += (size_t)kN * 64;   // stride 64: shift-addressable
  float*  erbuf = ws + o; o += (size_t)kN * 64;
  __bf16* z     = (__bf16*)(ws + o); o += (size_t)kR * kN * kHID / 2;  // [r][N][128]
  __bf16* wt    = (__bf16*)(ws + o); o += 327680 / 2;
  // zero-region: degcur (6N ints) + stats (640 f32), one memset
  int* degcur   = (int*)(ws + o); o += (size_t)6 * kN;
  float* stats  = ws + o; o += 640;   // [e1:256][m1_l0:128][m1_l1:128][d1:128]
  int* rowptr   = (int*)(ws + o); o += (size_t)kR * (kN + 1);
  int* colidx   = (int*)(ws + o); o += (size_t)kR * kE;
  (void)ws_size; (void)in_sizes; (void)n_in; (void)out_size;

  int* deg    = degcur;
  int* cursor = degcur + 3 * kN;
  float* stat_e1 = stats;
  float* stat_m1[2] = {stats + 256, stats + 384};
  float* stat_d1 = stats + 512;

  // wt offsets (__bf16 elements; each matrix: hi[m][k] then lo[m][k])
  const long kWE1 = 0, kWE2 = 16384, kWZ = 49152;
  const long kWM1_0 = 245760, kWM1_1 = 262144, kWM2_0 = 278528, kWM2_1 = 294912, kWD1 = 311296;

  auto nb = [](long t) { return (int)((t + 255) / 256); };
  const dim3 gE(nb(kE), kR);
  const dim3 gP(nb(kE), 16);                 // prep: y<13 wprep, y>=13 hist
  const dim3 gM128((kN + 63) / 64, 2, 1);    // BM=64: 626 blocks
  const dim3 gM64((kN + 63) / 64, 1, 1);     // 313 blocks
  const dim3 gMZ((kN + 63) / 64, 2, kR);     // 1878 blocks
  const float invn = 1.0f / kN;
  float* F0 = nullptr; const float* cF0 = nullptr;

  // ---- prep: zero memset, then combined wprep+hist, scan, scatter ----
  WDescs wd;
  wd.d[0] = {e1_W, kWE1, kIN, kHID};
  wd.d[1] = {e2_W, kWE2, kHID, kHID};
  for (int i = 0; i < 6; i++) wd.d[2 + i] = {gat_W + (size_t)i * 16384, kWZ + (long)i * 32768, kHID, kHID};
  wd.d[8]  = {m1_W,        kWM1_0, kHID, kHD2};
  wd.d[9]  = {m1_W + 8192, kWM1_1, kHID, kHD2};
  wd.d[10] = {m2_W,        kWM2_0, kHD2, kHID};
  wd.d[11] = {m2_W + 8192, kWM2_1, kHD2, kHID};
  wd.d[12] = {d1_W,        kWD1,   kHID, kHD2};
  hipMemsetAsync(degcur, 0, ((size_t)6 * kN + 640) * sizeof(int), stream);
  prep_kernel<<<gP, 256, 0, stream>>>(wd, wt, dst, deg);
  csr_scan_kernel<<<dim3(1, kR), 1024, 0, stream>>>(deg, rowptr);
  scatter_kernel<<<gE, 256, 0, stream>>>(src, dst, rowptr, cursor, colidx);

  // ---- embed MLP (skip=True) ----
  mgemm_kernel<3><<<gM128, 256, 0, stream>>>(inputs, wt + kWE1, e1_b, cF0, 0,
                                          cF0, cF0, cF0, invn, stat_e1, bufA, nullptr,
                                          cF0, cF0, F0, F0, kN, kIN, kHID, 0, 0);
  mgemm_kernel<3><<<gM128, 256, 0, stream>>>(bufA, wt + kWE2, e2_b, bufA, 2,
                                          stat_e1, e_g, e_bt, invn, F0, h, nullptr,
                                          cF0, cF0, F0, F0, kN, kHID, kHID, 0, 0);

  for (int l = 0; l < kL; l++) {
    // z projections: 2-pass split (output stored bf16; r13 evidence absmax 0.0039)
    mgemm_kernel<2><<<gMZ, 256, 0, stream>>>(h, wt + kWZ + (long)l * 3 * 32768, cF0, cF0, 0,
                                          cF0, cF0, cF0, invn, F0, F0, z,
                                          gat_al + (size_t)l * kR * kHID,
                                          gat_ar + (size_t)l * kR * kHID, elbuf, erbuf,
                                          kN, kHID, kHID, 32768, (long)kN * kHID);
    gat3_kernel<<<nb((long)kN * kH), 256, 0, stream>>>(rowptr, colidx, (const ushort*)z,
                                             elbuf, erbuf,
                                             attn_p + (size_t)l * kR * kHID,
                                             gat_b + (size_t)l * kR * kHID, vv);
    mgemm_kernel<3><<<gM64, 256, 0, stream>>>(vv, wt + (l ? kWM1_1 : kWM1_0),
                                           m1_b + (size_t)l * kHD2, cF0, 0,
                                           cF0, cF0, cF0, invn, stat_m1[l], bufA, nullptr,
                                           cF0, cF0, F0, F0, kN, kHID, kHD2, 0, 0);
    mgemm_kernel<3><<<gM128, 256, 0, stream>>>(bufA, wt + (l ? kWM2_1 : kWM2_0),
                                            m2_b + (size_t)l * kHID, h, 1,
                                            stat_m1[l], m_g + (size_t)l * kHD2,
                                            m_bt + (size_t)l * kHD2, invn, F0, h, nullptr,
                                            cF0, cF0, F0, F0, kN, kHD2, kHID, 0, 0);
  }

  // ---- decode MLP ----
  mgemm_kernel<3><<<gM64, 256, 0, stream>>>(h, wt + kWD1, d1_b, cF0, 0,
                                         cF0, cF0, cF0, invn, stat_d1, bufA, nullptr,
                                         cF0, cF0, F0, F0, kN, kHID, kHD2, 0, 0);
  gemv_out_kernel<<<nb(kN), 256, 0, stream>>>(bufA, stat_d1, d_g, d_bt, invn,
                                              d2_W, d2_b, (float*)d_out, kN, kHD2);
}

// Round 16
// 304.591 us; speedup vs baseline: 1.1276x; 1.0035x over previous
//
#include <hip/hip_runtime.h>
#include <math.h>

// ---- problem constants ----
constexpr int kN   = 20000;
constexpr int kE   = 160000;
constexpr int kR   = 3;
constexpr int kL   = 2;
constexpr int kIN  = 64;
constexpr int kHID = 128;
constexpr int kH   = 16;
constexpr int kFH  = 8;
constexpr int kHD2 = 64;

typedef __bf16 bf16x8 __attribute__((ext_vector_type(8)));
typedef float  f32x4  __attribute__((ext_vector_type(4)));

__device__ __forceinline__ bf16x8 ldfrag(const __bf16* p) {
  return __builtin_bit_cast(bf16x8, *(const uint4*)p);
}
__device__ __forceinline__ f32x4 MF(bf16x8 a, bf16x8 b, f32x4 c) {
  return __builtin_amdgcn_mfma_f32_16x16x32_bf16(a, b, c, 0, 0, 0);
}

// split 8 f32 values into bf16 hi/lo fragments
__device__ __forceinline__ void splitx(const float* x, bf16x8& hi, bf16x8& lo) {
  union { __bf16 b[8]; bf16x8 v; } uh, ul;
#pragma unroll
  for (int e = 0; e < 8; e++) {
    __bf16 hb = (__bf16)x[e];
    uh.b[e] = hb;
    ul.b[e] = (__bf16)(x[e] - (float)hb);
  }
  hi = uh.v; lo = ul.v;
}

// ============================================================================
// MFMA GEMM, bf16-split: C = [BN+ReLU?](A) @ W (+bias)(+res)
// BM=64 tile (4 waves x 16 rows, acc[4]); BP=3 ~f32 precision, BP=2 skips
// the ah*bl pass + Bl LDS (z-gemm: output stored bf16 anyway).
// SUM3: A = A0 + A0+astride + A0+2*astride (relation-partial vv sum, in-load).
// el/er epilogue (z-gemm): elb/erb[row*64 + rel*16 + head] from exact f32 acc.
// ============================================================================
template <int BP, bool SUM3>
__global__ __launch_bounds__(256) void mgemm_kernel(
    const float* __restrict__ A, const __bf16* __restrict__ WT,
    const float* __restrict__ bias, const float* __restrict__ resf, int resmode,
    const float* __restrict__ bnstat, const float* __restrict__ bng,
    const float* __restrict__ bnbt, float invn,
    float* __restrict__ statS,
    float* __restrict__ Cf, __bf16* __restrict__ Chi,
    const float* __restrict__ alb, const float* __restrict__ arb,
    float* __restrict__ elb, float* __restrict__ erb,
    int n, int k, int m, long wstride, long cstride, long astride) {
  __shared__ __bf16 Bh[64][136];                       // +8 pad -> conflict-free
  __shared__ __bf16 Bl[(BP == 3) ? 64 : 1][136];       // elided for BP=2
  __shared__ float scS[128], shS[128];
  const int t  = threadIdx.x;
  const int w  = t >> 6;
  const int l  = t & 63;
  const int lr = l & 15;
  const int lg = l >> 4;
  const int rb = blockIdx.x * 64 + w * 16;             // BM=64: wave owns 16 rows
  const int c0 = blockIdx.y * 64;
  const __bf16* Whi = WT + (size_t)blockIdx.z * wstride;
  const __bf16* Wlo = Whi + (size_t)k * m;
  if (Chi) Chi += (size_t)blockIdx.z * cstride;
  const float* al = alb ? alb + blockIdx.z * kHID : nullptr;
  const float* ar = arb ? arb + blockIdx.z * kHID : nullptr;
  if (elb) { elb += blockIdx.z * 16; erb += blockIdx.z * 16; }

  const bool bn = bnstat != nullptr;
  if (bn && t < k) {
    float mu  = bnstat[t] * invn;
    float var = bnstat[k + t] * invn - mu * mu;
    float s = bng[t] * rsqrtf(var + 1e-5f);
    scS[t] = s; shS[t] = bnbt[t] - mu * s;
  }
  const int kseg = k >> 3;
  for (int idx = t; idx < 64 * kseg; idx += 256) {
    int col = idx / kseg, seg = idx - col * kseg;
    *(uint4*)&Bh[col][seg * 8] = *(const uint4*)&Whi[(size_t)(c0 + col) * k + seg * 8];
    if constexpr (BP == 3)
      *(uint4*)&Bl[col][seg * 8] = *(const uint4*)&Wlo[(size_t)(c0 + col) * k + seg * 8];
  }
  __syncthreads();

  int r0 = rb + lr; if (r0 > n - 1) r0 = n - 1;
  f32x4 acc[4] = {};

  for (int ks = 0; ks < (k >> 5); ks++) {
    const int koff = ks * 32 + lg * 8;
    const float* p0 = &A[(size_t)r0 * k + koff];
    float x[8];
    {
      float4 xa = *(const float4*)p0;
      float4 xb = *(const float4*)(p0 + 4);
      x[0] = xa.x; x[1] = xa.y; x[2] = xa.z; x[3] = xa.w;
      x[4] = xb.x; x[5] = xb.y; x[6] = xb.z; x[7] = xb.w;
    }
    if constexpr (SUM3) {
      float4 ya = *(const float4*)(p0 + astride);
      float4 yb = *(const float4*)(p0 + astride + 4);
      float4 za = *(const float4*)(p0 + 2 * astride);
      float4 zb = *(const float4*)(p0 + 2 * astride + 4);
      x[0] += ya.x + za.x; x[1] += ya.y + za.y; x[2] += ya.z + za.z; x[3] += ya.w + za.w;
      x[4] += yb.x + zb.x; x[5] += yb.y + zb.y; x[6] += yb.z + zb.z; x[7] += yb.w + zb.w;
    }
    if (bn) {
#pragma unroll
      for (int e = 0; e < 8; e++)
        x[e] = fmaxf(fmaf(x[e], scS[koff + e], shS[koff + e]), 0.f);
    }
    bf16x8 a0h, a0l;
    splitx(x, a0h, a0l);
#pragma unroll
    for (int j = 0; j < 4; j++) {
      bf16x8 bh = ldfrag(&Bh[j * 16 + lr][koff]);
      acc[j] = MF(a0h, bh, acc[j]);
      acc[j] = MF(a0l, bh, acc[j]);
      if constexpr (BP == 3) {
        bf16x8 bl = ldfrag(&Bl[j * 16 + lr][koff]);
        acc[j] = MF(a0h, bl, acc[j]);
      }
    }
  }

  // epilogue: D element (j,q) -> row rb+lg*4+q, col c0+j*16+lr
  float s[4] = {}, s2[4] = {};
#pragma unroll
  for (int q = 0; q < 4; q++) {
    int row = rb + lg * 4 + q;
    bool ok = row < n;
#pragma unroll
    for (int j = 0; j < 4; j++) {
      int col = c0 + j * 16 + lr;
      float v = acc[j][q];
      if (bias) v += bias[col];
      size_t off = (size_t)row * m + col;
      if (ok) {
        if (resmode == 1) v += resf[off];
        else if (resmode == 2) v += fmaxf(fmaf(resf[off], scS[col], shS[col]), 0.f);
        if (Cf) Cf[off] = v;
        if (Chi) Chi[off] = (__bf16)v;
        s[j] += v; s2[j] += v * v;
      }
    }
  }
  if (statS) {
    __syncthreads();
    float* red = (float*)&Bh[0][0];   // 512 floats scratch
#pragma unroll
    for (int j = 0; j < 4; j++) {
      float a = s[j], b = s2[j];
      a += __shfl_xor(a, 16, 64); a += __shfl_xor(a, 32, 64);
      b += __shfl_xor(b, 16, 64); b += __shfl_xor(b, 32, 64);
      if (lg == 0) { red[w * 64 + j * 16 + lr] = a; red[256 + w * 64 + j * 16 + lr] = b; }
    }
    __syncthreads();
    if (t < 64) {
      float a = red[t] + red[64 + t] + red[128 + t] + red[192 + t];
      float b = red[256 + t] + red[320 + t] + red[384 + t] + red[448 + t];
      atomicAdd(&statS[c0 + t], a);
      atomicAdd(&statS[m + c0 + t], b);
    }
  }
  if (al) {
#pragma unroll
    for (int q = 0; q < 4; q++) {
      int row = rb + lg * 4 + q;
#pragma unroll
      for (int j = 0; j < 4; j++) {
        int col = c0 + j * 16 + lr;
        float zv = acc[j][q];
        float pl = zv * al[col];
        float pr = zv * ar[col];
        pl += __shfl_xor(pl, 1, 64); pl += __shfl_xor(pl, 2, 64); pl += __shfl_xor(pl, 4, 64);
        pr += __shfl_xor(pr, 1, 64); pr += __shfl_xor(pr, 2, 64); pr += __shfl_xor(pr, 4, 64);
        if ((lr & 7) == 0 && row < n) {
          int hd = col >> 3;   // global head 0..15
          elb[((size_t)row << 6) + hd] = pl;
          erb[((size_t)row << 6) + hd] = pr;
        }
      }
    }
  }
}

// ---- combined prep: weight transpose+split (y<13) and dst histogram (y>=13) ----
struct WDesc { const float* src; long doff; int k, m; };
struct WDescs { WDesc d[13]; };
__global__ void prep_kernel(WDescs ds, __bf16* __restrict__ wt,
                            const int* __restrict__ dst, int* __restrict__ deg) {
  int y = blockIdx.y;
  if (y < 13) {
    WDesc dd = ds.d[y];
    int idx = blockIdx.x * 256 + threadIdx.x;
    if (idx >= dd.k * dd.m) return;
    int row = idx / dd.m, col = idx - row * dd.m;
    float v = dd.src[idx];
    __bf16 hb = (__bf16)v;
    __bf16 lb = (__bf16)(v - (float)hb);
    wt[dd.doff + (size_t)col * dd.k + row] = hb;
    wt[dd.doff + (size_t)dd.k * dd.m + (size_t)col * dd.k + row] = lb;
  } else {
    int r = y - 13;
    int e = blockIdx.x * 256 + threadIdx.x;
    if (e < kE) atomicAdd(&deg[r * kN + dst[r * kE + e]], 1);
  }
}

__global__ __launch_bounds__(1024) void csr_scan_kernel(const int* __restrict__ deg,
                                                        int* __restrict__ rowptr) {
  const int r = blockIdx.y;
  const int* dg = deg + r * kN;
  int* rp = rowptr + r * (kN + 1);
  const int t = threadIdx.x;
  constexpr int C = (kN + 1023) / 1024;   // 20
  const int base = t * C;
  int sum = 0;
#pragma unroll
  for (int i = 0; i < C; i++) {
    int j = base + i;
    if (j < kN) sum += dg[j];
  }
  __shared__ int warpTot[16];
  int lane = t & 63, wid = t >> 6;
  int v = sum;
  for (int off = 1; off < 64; off <<= 1) {
    int y = __shfl_up(v, off, 64);
    if (lane >= off) v += y;
  }
  if (lane == 63) warpTot[wid] = v;
  __syncthreads();
  int wadd = 0;
#pragma unroll
  for (int i = 0; i < 16; i++) if (i < wid) wadd += warpTot[i];
  int run = wadd + v - sum;
#pragma unroll
  for (int i = 0; i < C; i++) {
    int j = base + i;
    if (j < kN) { rp[j] = run; run += dg[j]; }
  }
  if (t == 1023) rp[kN] = run;
}

__global__ void scatter_kernel(const int* __restrict__ src, const int* __restrict__ dst,
                               const int* __restrict__ rowptr, int* __restrict__ cursor,
                               int* __restrict__ col) {
  int r = blockIdx.y;
  int e = blockIdx.x * 256 + threadIdx.x;
  if (e < kE) {
    int d = dst[r * kE + e];
    int p = atomicAdd(&cursor[r * kN + d], 1);
    col[r * kE + rowptr[r * (kN + 1) + d] + p] = src[r * kE + e];
  }
}

// ---- fused relation-softmax + edge softmax + aggregation, SPLIT BY RELATION ----
// block y = relation; thread per (dst, head). 3x thread count vs fused-relation
// version -> better latency hiding; writes relation-partial vvp[r] (no conflict);
// m1 sums the three partials in its A-load (SUM3). Masked 8-wide edge batches.
__global__ void gat3_kernel(const int* __restrict__ rowptr, const int* __restrict__ colidx,
                            const ushort* __restrict__ z, const float* __restrict__ elb,
                            const float* __restrict__ erb,
                            const float* __restrict__ attn_pl, const float* __restrict__ gat_bl,
                            float* __restrict__ vvp) {
  __shared__ float wpS[kHID], cvecS[kHID];
  const int r = blockIdx.y;
  int t = threadIdx.x;
  if (t < kHID) {
    float p0 = attn_pl[t], p1 = attn_pl[kHID + t], p2 = attn_pl[2 * kHID + t];
    float mx = fmaxf(p0, fmaxf(p1, p2));
    float e0 = __expf(p0 - mx), e1 = __expf(p1 - mx), e2 = __expf(p2 - mx);
    float si = 1.f / (e0 + e1 + e2);
    float wr = (r == 0 ? e0 : r == 1 ? e1 : e2) * si;
    wpS[t] = wr;
    cvecS[t] = (r == 0) ? (e0 * gat_bl[t] + e1 * gat_bl[kHID + t] + e2 * gat_bl[2 * kHID + t]) * si
                        : 0.f;
  }
  __syncthreads();
  int idx = blockIdx.x * 256 + t;
  if (idx >= kN * kH) return;
  int d = idx >> 4, hh = idx & 15;
  const int fo = hh << 3;
  const int* rp = rowptr + r * (kN + 1);
  const int* ci = colidx + (size_t)r * kE;
  const ushort* zr = z + (size_t)r * kN * kHID;
  const int ro = r * 16 + hh;
  float erd = erb[((size_t)d << 6) + ro];
  int beg = rp[d], end = rp[d + 1];
  float s = 0.f;
  float acc[kFH] = {};
  for (int p = beg; p < end; p += 8) {
    int q[8]; float ev[8]; uint4 zz[8];
#pragma unroll
    for (int u = 0; u < 8; u++) {
      int pp = p + u;
      q[u] = ci[pp < end ? pp : (end > beg ? end - 1 : 0)];
    }
#pragma unroll
    for (int u = 0; u < 8; u++) ev[u] = elb[((size_t)q[u] << 6) + ro];
#pragma unroll
    for (int u = 0; u < 8; u++) zz[u] = *(const uint4*)(zr + ((size_t)q[u] << 7) + fo);
#pragma unroll
    for (int u = 0; u < 8; u++) {
      float v = ev[u] + erd;
      v = v > 0.f ? v : 0.2f * v;
      float ex = (p + u < end) ? __expf(v) : 0.f;   // logits O(0.1): no overflow
      s += ex;
      acc[0] = fmaf(ex, __uint_as_float(zz[u].x << 16),         acc[0]);
      acc[1] = fmaf(ex, __uint_as_float(zz[u].x & 0xffff0000u), acc[1]);
      acc[2] = fmaf(ex, __uint_as_float(zz[u].y << 16),         acc[2]);
      acc[3] = fmaf(ex, __uint_as_float(zz[u].y & 0xffff0000u), acc[3]);
      acc[4] = fmaf(ex, __uint_as_float(zz[u].z << 16),         acc[4]);
      acc[5] = fmaf(ex, __uint_as_float(zz[u].z & 0xffff0000u), acc[5]);
      acc[6] = fmaf(ex, __uint_as_float(zz[u].w << 16),         acc[6]);
      acc[7] = fmaf(ex, __uint_as_float(zz[u].w & 0xffff0000u), acc[7]);
    }
  }
  float inv = s > 0.f ? 1.f / s : 0.f;
  float out[kFH];
#pragma unroll
  for (int f = 0; f < kFH; f++)
    out[f] = fmaf(wpS[fo + f] * inv, acc[f], cvecS[fo + f]);
  float4* vp = (float4*)(vvp + (size_t)r * kN * kHID + ((size_t)d << 7) + fo);
  vp[0] = make_float4(out[0], out[1], out[2], out[3]);
  vp[1] = make_float4(out[4], out[5], out[6], out[7]);
}

// ---- final gemv: BN fold from raw stats + BN+ReLU + dot, all fused ----
__global__ void gemv_out_kernel(const float* __restrict__ A, const float* __restrict__ statS,
                                const float* __restrict__ g, const float* __restrict__ bt,
                                float invn, const float* __restrict__ w,
                                const float* __restrict__ b, float* __restrict__ out,
                                int n, int k) {
  __shared__ float scS[kHD2], shS[kHD2];
  int t = threadIdx.x;
  if (t < k) {
    float mu  = statS[t] * invn;
    float var = statS[k + t] * invn - mu * mu;
    float s = g[t] * rsqrtf(var + 1e-5f);
    scS[t] = s; shS[t] = bt[t] - mu * s;
  }
  __syncthreads();
  int i = blockIdx.x * 256 + t;
  if (i >= n) return;
  const float4* a = (const float4*)(A + (size_t)i * k);
  float acc = b[0];
  for (int j4 = 0; j4 < k / 4; j4++) {
    float4 x = a[j4];
    int c = j4 * 4;
    acc = fmaf(fmaxf(fmaf(x.x, scS[c],     shS[c]),     0.f), w[c],     acc);
    acc = fmaf(fmaxf(fmaf(x.y, scS[c + 1], shS[c + 1]), 0.f), w[c + 1], acc);
    acc = fmaf(fmaxf(fmaf(x.z, scS[c + 2], shS[c + 2]), 0.f), w[c + 2], acc);
    acc = fmaf(fmaxf(fmaf(x.w, scS[c + 3], shS[c + 3]), 0.f), w[c + 3], acc);
  }
  out[i] = acc;
}

extern "C" void kernel_launch(void* const* d_in, const int* in_sizes, int n_in,
                              void* d_out, int out_size, void* d_ws, size_t ws_size,
                              hipStream_t stream) {
  const float* inputs = (const float*)d_in[0];
  const int*   src    = (const int*)d_in[1];
  const int*   dst    = (const int*)d_in[2];
  const float* e1_W   = (const float*)d_in[3];
  const float* e1_b   = (const float*)d_in[4];
  const float* e_g    = (const float*)d_in[5];
  const float* e_bt   = (const float*)d_in[6];
  const float* e2_W   = (const float*)d_in[7];
  const float* e2_b   = (const float*)d_in[8];
  const float* gat_W  = (const float*)d_in[9];
  const float* gat_al = (const float*)d_in[10];
  const float* gat_ar = (const float*)d_in[11];
  const float* gat_b  = (const float*)d_in[12];
  const float* attn_p = (const float*)d_in[13];
  const float* m1_W   = (const float*)d_in[14];
  const float* m1_b   = (const float*)d_in[15];
  const float* m_g    = (const float*)d_in[16];
  const float* m_bt   = (const float*)d_in[17];
  const float* m2_W   = (const float*)d_in[18];
  const float* m2_b   = (const float*)d_in[19];
  const float* d1_W   = (const float*)d_in[20];
  const float* d1_b   = (const float*)d_in[21];
  const float* d_g    = (const float*)d_in[22];
  const float* d_bt   = (const float*)d_in[23];
  const float* d2_W   = (const float*)d_in[24];
  const float* d2_b   = (const float*)d_in[25];

  float* ws = (float*)d_ws;
  size_t o = 0;
  float*  h     = ws + o; o += (size_t)kN * kHID;
  float*  bufA  = ws + o; o += (size_t)kN * kHID;
  float*  vvp   = ws + o; o += (size_t)kR * kN * kHID;   // relation-partial vv
  float*  elbuf = ws + o; o += (size_t)kN * 64;
  float*  erbuf = ws + o; o += (size_t)kN * 64;
  __bf16* z     = (__bf16*)(ws + o); o += (size_t)kR * kN * kHID / 2;  // [r][N][128]
  __bf16* wt    = (__bf16*)(ws + o); o += 327680 / 2;
  // zero-region: degcur (6N ints) + stats (640 f32), one memset
  int* degcur   = (int*)(ws + o); o += (size_t)6 * kN;
  float* stats  = ws + o; o += 640;   // [e1:256][m1_l0:128][m1_l1:128][d1:128]
  int* rowptr   = (int*)(ws + o); o += (size_t)kR * (kN + 1);
  int* colidx   = (int*)(ws + o); o += (size_t)kR * kE;
  (void)ws_size; (void)in_sizes; (void)n_in; (void)out_size;

  int* deg    = degcur;
  int* cursor = degcur + 3 * kN;
  float* stat_e1 = stats;
  float* stat_m1[2] = {stats + 256, stats + 384};
  float* stat_d1 = stats + 512;

  // wt offsets (__bf16 elements; each matrix: hi[m][k] then lo[m][k])
  const long kWE1 = 0, kWE2 = 16384, kWZ = 49152;
  const long kWM1_0 = 245760, kWM1_1 = 262144, kWM2_0 = 278528, kWM2_1 = 294912, kWD1 = 311296;

  auto nb = [](long t) { return (int)((t + 255) / 256); };
  const dim3 gE(nb(kE), kR);
  const dim3 gP(nb(kE), 16);                 // prep: y<13 wprep, y>=13 hist
  const dim3 gM128((kN + 63) / 64, 2, 1);    // BM=64: 626 blocks
  const dim3 gM64((kN + 63) / 64, 1, 1);     // 313 blocks
  const dim3 gMZ((kN + 63) / 64, 2, kR);     // 1878 blocks
  const dim3 gG3(nb((long)kN * kH), kR);     // 3750 blocks
  const float invn = 1.0f / kN;
  float* F0 = nullptr; const float* cF0 = nullptr;

  // ---- prep: zero memset, then combined wprep+hist, scan, scatter ----
  WDescs wd;
  wd.d[0] = {e1_W, kWE1, kIN, kHID};
  wd.d[1] = {e2_W, kWE2, kHID, kHID};
  for (int i = 0; i < 6; i++) wd.d[2 + i] = {gat_W + (size_t)i * 16384, kWZ + (long)i * 32768, kHID, kHID};
  wd.d[8]  = {m1_W,        kWM1_0, kHID, kHD2};
  wd.d[9]  = {m1_W + 8192, kWM1_1, kHID, kHD2};
  wd.d[10] = {m2_W,        kWM2_0, kHD2, kHID};
  wd.d[11] = {m2_W + 8192, kWM2_1, kHD2, kHID};
  wd.d[12] = {d1_W,        kWD1,   kHID, kHD2};
  hipMemsetAsync(degcur, 0, ((size_t)6 * kN + 640) * sizeof(int), stream);
  prep_kernel<<<gP, 256, 0, stream>>>(wd, wt, dst, deg);
  csr_scan_kernel<<<dim3(1, kR), 1024, 0, stream>>>(deg, rowptr);
  scatter_kernel<<<gE, 256, 0, stream>>>(src, dst, rowptr, cursor, colidx);

  // ---- embed MLP (skip=True) ----
  mgemm_kernel<3, false><<<gM128, 256, 0, stream>>>(inputs, wt + kWE1, e1_b, cF0, 0,
                                          cF0, cF0, cF0, invn, stat_e1, bufA, nullptr,
                                          cF0, cF0, F0, F0, kN, kIN, kHID, 0, 0, 0);
  mgemm_kernel<3, false><<<gM128, 256, 0, stream>>>(bufA, wt + kWE2, e2_b, bufA, 2,
                                          stat_e1, e_g, e_bt, invn, F0, h, nullptr,
                                          cF0, cF0, F0, F0, kN, kHID, kHID, 0, 0, 0);

  for (int l = 0; l < kL; l++) {
    // z projections: 2-pass split (output stored bf16; r13 evidence absmax 0.0039)
    mgemm_kernel<2, false><<<gMZ, 256, 0, stream>>>(h, wt + kWZ + (long)l * 3 * 32768, cF0, cF0, 0,
                                          cF0, cF0, cF0, invn, F0, F0, z,
                                          gat_al + (size_t)l * kR * kHID,
                                          gat_ar + (size_t)l * kR * kHID, elbuf, erbuf,
                                          kN, kHID, kHID, 32768, (long)kN * kHID, 0);
    gat3_kernel<<<gG3, 256, 0, stream>>>(rowptr, colidx, (const ushort*)z,
                                             elbuf, erbuf,
                                             attn_p + (size_t)l * kR * kHID,
                                             gat_b + (size_t)l * kR * kHID, vvp);
    // m1: sums the 3 relation-partial vv buffers in its A-load (SUM3)
    mgemm_kernel<3, true><<<gM64, 256, 0, stream>>>(vvp, wt + (l ? kWM1_1 : kWM1_0),
                                           m1_b + (size_t)l * kHD2, cF0, 0,
                                           cF0, cF0, cF0, invn, stat_m1[l], bufA, nullptr,
                                           cF0, cF0, F0, F0, kN, kHID, kHD2, 0, 0,
                                           (long)kN * kHID);
    mgemm_kernel<3, false><<<gM128, 256, 0, stream>>>(bufA, wt + (l ? kWM2_1 : kWM2_0),
                                            m2_b + (size_t)l * kHID, h, 1,
                                            stat_m1[l], m_g + (size_t)l * kHD2,
                                            m_bt + (size_t)l * kHD2, invn, F0, h, nullptr,
                                            cF0, cF0, F0, F0, kN, kHD2, kHID, 0, 0, 0);
  }

  // ---- decode MLP ----
  mgemm_kernel<3, false><<<gM64, 256, 0, stream>>>(h, wt + kWD1, d1_b, cF0, 0,
                                         cF0, cF0, cF0, invn, stat_d1, bufA, nullptr,
                                         cF0, cF0, F0, F0, kN, kHID, kHD2, 0, 0, 0);
  gemv_out_kernel<<<nb(kN), 256, 0, stream>>>(bufA, stat_d1, d_g, d_bt, invn,
                                              d2_W, d2_b, (float*)d_out, kN, kHD2);
}